// Round 3
// baseline (425.413 us; speedup 1.0000x reference)
//
#include <hip/hip_runtime.h>
#include <stdint.h>

typedef unsigned short u16;
typedef __bf16 bf16x8 __attribute__((ext_vector_type(8)));
typedef float f32x4 __attribute__((ext_vector_type(4)));

// ---------- helpers ----------
__device__ __forceinline__ u16 f2b(float f) {
  union { float f; uint32_t u; } v; v.f = f;
  uint32_t r = v.u + 0x7fffu + ((v.u >> 16) & 1u);
  return (u16)(r >> 16);
}
__device__ __forceinline__ float b2f(u16 b) {
  union { float f; uint32_t u; } v; v.u = ((uint32_t)b) << 16;
  return v.f;
}
// async 16B/lane global->LDS (dest = uniform base + lane*16)
__device__ __forceinline__ void g2l16(const void* g, void* l) {
  __builtin_amdgcn_global_load_lds(
      (const __attribute__((address_space(1))) void*)g,
      (__attribute__((address_space(3))) void*)l, 16, 0, 0);
}

#define N_SAMP 128
#define OPAD   224
#define ROWS   (N_SAMP * OPAD)   // 28672

// ---------- K0a: weight repack ----------
__global__ __launch_bounds__(256) void prep_weights(
    const float* __restrict__ conv_w, const float* __restrict__ hp_w0,
    const float* __restrict__ gt_w0, const float* __restrict__ gt_w1,
    u16* __restrict__ W2, u16* __restrict__ hp_w0t,
    u16* __restrict__ gt_w0t, u16* __restrict__ gt_w1t) {
  int idx = blockIdx.x * 256 + threadIdx.x;
  const int nW2 = 9 * 128 * 1024;
  const int nHP = 256 * 288;
  const int nGT0 = 256 * 288;
  const int nGT1 = 256 * 256;
  if (idx < nW2) {
    int s = idx / 131072; int r = idx & 131071;
    int cf = r >> 10; int cin = r & 1023;
    W2[idx] = f2b(conv_w[(cf * 1024 + cin) * 9 + s]);
    return;
  }
  idx -= nW2;
  if (idx < nHP) {
    int nn = idx / 288, kk = idx % 288;
    hp_w0t[nn * 288 + kk] = (kk < 258) ? f2b(hp_w0[kk * 256 + nn]) : (u16)0;
    return;
  }
  idx -= nHP;
  if (idx < nGT0) {
    int nn = idx / 288, kk = idx % 288;
    gt_w0t[nn * 288 + kk] = (kk < 258) ? f2b(gt_w0[kk * 256 + nn]) : (u16)0;
    return;
  }
  idx -= nGT0;
  if (idx < nGT1) {
    int nn = idx >> 8, kk = idx & 255;
    gt_w1t[nn * 256 + kk] = f2b(gt_w1[kk * 256 + nn]);
  }
}

// ---------- K0b: image -> imgT[n][256 sp (16x16 zero-bordered)][1024 cin] bf16 ----------
__global__ __launch_bounds__(256) void prep_img(const float* __restrict__ image,
                                                u16* __restrict__ imgT) {
  __shared__ float t[64][197];
  int n = blockIdx.x >> 4;
  int cin0 = (blockIdx.x & 15) * 64;
  const float* src = image + ((size_t)n * 1024 + cin0) * 196;
  for (int e = threadIdx.x; e < 64 * 196; e += 256) {
    int c = e / 196, sp = e % 196;
    t[c][sp] = src[c * 196 + sp];
  }
  __syncthreads();
  int w = threadIdx.x >> 6, lane = threadIdx.x & 63;
  for (int i = 0; i < 64; ++i) {
    int spg = i * 4 + w;
    int gy = spg >> 4, gx = spg & 15;
    float v = 0.f;
    if (gy >= 1 && gy <= 14 && gx >= 1 && gx <= 14) v = t[lane][(gy - 1) * 14 + (gx - 1)];
    imgT[(((size_t)(n * 256 + spg)) << 10) + cin0 + lane] = f2b(v);
  }
}

// ---------- K2: qeb cols 128..287 (+ zero padded rows' cols 0..127) ----------
__global__ __launch_bounds__(256) void fill_qe(const float* __restrict__ code,
                                               u16* __restrict__ qeb) {
  int base = blockIdx.x * 8;
  for (int rr = 0; rr < 8; ++rr) {
    int r = base + rr;
    int n = r / 224, o = r % 224;
    int y = o / 14, x = o % 14;
    bool valid = o < 196;
    u16* row = qeb + (size_t)r * 288;
    for (int c = threadIdx.x; c < 288; c += 256) {
      u16 v;
      if (c < 128) { if (valid) continue; v = 0; }
      else if (c == 128) v = valid ? f2b(-1.f + 2.f * y / 13.f) : (u16)0;
      else if (c == 129) v = valid ? f2b(-1.f + 2.f * x / 13.f) : (u16)0;
      else if (c < 258) v = valid ? f2b(code[n * 128 + (c - 130)]) : (u16)0;
      else v = 0;
      row[c] = v;
    }
  }
}

// ---------- K1: conv as implicit GEMM with 9-tap A-reuse ----------
// Block = full n: M=224 (2 wm x 112), N=128 (2 wn x 64), K split 4 over cin.
// grid 512 = 128 n x 4 ks = 2 blocks/CU. Per cin-block of 32:
//   A = full 16x16 spatial grid x 32 cin staged ONCE (16 KB), reused by all 9 taps
//   (tap = pure LDS row shift dy*16+dx). B (128 cols x 32 cin) staged per tap, ring-4.
// One barrier per step; counted vmcnt (4 normally, 8 around A-prefetch), never 0 mid-loop.
// XCD map: ks = xcd>>1, so an XCD's 64 blocks share one 590 KB W2 slice (L2-hot).
__global__ __launch_bounds__(256) void conv_gemm(
    const u16* __restrict__ imgT, const u16* __restrict__ W2,
    float* __restrict__ convAcc) {
  __shared__ __align__(16) u16 lA[2][256 * 32];   // 2 x 16 KB, dbuf per cin-block
  __shared__ __align__(16) u16 lB[4][128 * 32];   // 4 x 8 KB ring, per (cin-block, tap)
  int tid = threadIdx.x, lane = tid & 63, w = tid >> 6;
  int wg = blockIdx.x;
  int xcd = wg & 7;
  int ks = xcd >> 1;                       // K-split id 0..3 (cin slice of 256)
  int n = ((wg >> 3) << 1) | (xcd & 1);
  int kbase = ks << 3;                     // base cin-block (cb32 units, 8 per ks)
  size_t nBase = (size_t)n << 8;
  int wm = w >> 1, wn = w & 1;             // wave tile: rows wm*112.., cols wn*64..
  int rowIn = lane >> 2;                   // staging: 16 rows/instr, 4 lanes (64B) per row
  int swz = (((lane & 3) ^ ((rowIn >> 1) & 3)) << 3);  // pre-swizzled source chunk (elems)

  int l = lane & 15, q = lane >> 4;        // MFMA: row/col sel l, k-chunk q

  // per-lane A row base for each m-tile (grid position of output o); invalid -> 0
  int posB[7];
#pragma unroll
  for (int mt = 0; mt < 7; ++mt) {
    int o = wm * 112 + mt * 16 + l;
    int y = o / 14, x = o - y * 14;
    posB[mt] = (o < 196) ? (y * 16 + x) : 0;
  }

  f32x4 acc[7][4];
#pragma unroll
  for (int mt = 0; mt < 7; ++mt)
#pragma unroll
    for (int j = 0; j < 4; ++j) acc[mt][j] = (f32x4){0.f, 0.f, 0.f, 0.f};

  // A stage: 4 instrs/wave (wave w -> grid rows w*64 + ii*16), cbg = global cin-block
  auto STAGE_A = [&](int buf, int cbg) {
    int k0 = cbg << 5;
#pragma unroll
    for (int ii = 0; ii < 4; ++ii) {
      int r = w * 64 + ii * 16;
      g2l16(imgT + ((nBase + (size_t)(r + rowIn)) << 10) + k0 + swz,
            &lA[buf][r * 32]);
    }
  };
  // B stage: 2 instrs/wave (wave w -> cols w*32 + ii*16) for step ss
  auto STAGE_B = [&](int slot, int ss) {
    int cbg = kbase + ss / 9;
    int tp = ss - (ss / 9) * 9;
    int k0 = cbg << 5;
    const u16* Ws = W2 + (((size_t)tp * 128) << 10);
#pragma unroll
    for (int ii = 0; ii < 2; ++ii) {
      int c = w * 32 + ii * 16;
      g2l16(Ws + ((size_t)(c + rowIn) << 10) + k0 + swz, &lB[slot][c * 32]);
    }
  };

  // prologue: A(cb0):4 + B(0):2 + B(1):2 = 8 outstanding per wave
  STAGE_A(0, kbase);
  STAGE_B(0, 0);
  STAGE_B(1, 1);

  int tap = 0, tapOff = 0, cb = 0;   // cb local 0..7
#pragma unroll 1
  for (int s = 0; s < 72; ++s) {
    if (s + 2 < 72) STAGE_B((s + 2) & 3, s + 2);
    if (tap == 7 && cb < 7) STAGE_A((cb + 1) & 1, kbase + cb + 1);
    // counted waits: steady-state 4 in flight (B s+1, s+2); 8 around A prefetch
    if (s < 68) {
      if (tap >= 7) asm volatile("s_waitcnt vmcnt(8)" ::: "memory");
      else          asm volatile("s_waitcnt vmcnt(4)" ::: "memory");
    } else if (s < 70) {
      asm volatile("s_waitcnt vmcnt(4)" ::: "memory");
    } else if (s == 70) {
      asm volatile("s_waitcnt vmcnt(2)" ::: "memory");
    } else {
      asm volatile("s_waitcnt vmcnt(0)" ::: "memory");
    }
    __builtin_amdgcn_s_barrier();
    __builtin_amdgcn_sched_barrier(0);

    const char* aS = (const char*)lA[cb & 1];
    const char* bS = (const char*)lB[s & 3];
    bf16x8 af[7], bf[4];
#pragma unroll
    for (int mt = 0; mt < 7; ++mt) {
      int r = posB[mt] + tapOff;
      af[mt] = *(const bf16x8*)(aS + (r << 6) + (((q ^ (r >> 1)) & 3) << 4));
    }
#pragma unroll
    for (int j = 0; j < 4; ++j) {
      int rc = wn * 64 + j * 16 + l;
      bf[j] = *(const bf16x8*)(bS + (rc << 6) + (((q ^ (rc >> 1)) & 3) << 4));
    }
    asm volatile("s_waitcnt lgkmcnt(0)" ::: "memory");
    __builtin_amdgcn_sched_barrier(0);
    __builtin_amdgcn_s_setprio(1);
#pragma unroll
    for (int mt = 0; mt < 7; ++mt)
#pragma unroll
      for (int j = 0; j < 4; ++j)
        acc[mt][j] = __builtin_amdgcn_mfma_f32_16x16x32_bf16(af[mt], bf[j], acc[mt][j], 0, 0, 0);
    __builtin_amdgcn_s_setprio(0);
    __builtin_amdgcn_sched_barrier(0);

    if (++tap == 9) { tap = 0; tapOff = 0; ++cb; }
    else tapOff += ((tap == 3) | (tap == 6)) ? 14 : 1;
  }

  // epilogue: atomic fp32 accumulate of the K-slice partial
#pragma unroll
  for (int mt = 0; mt < 7; ++mt) {
    int o = wm * 112 + mt * 16 + q * 4;
#pragma unroll
    for (int j = 0; j < 4; ++j) {
      int col = wn * 64 + j * 16 + l;
#pragma unroll
      for (int r4 = 0; r4 < 4; ++r4) {
        if (o + r4 < 196)
          atomicAdd(convAcc + (size_t)(n * 224 + o + r4) * 128 + col, acc[mt][j][r4]);
      }
    }
  }
}

// ---------- K1b: convAcc + bias -> qeb bf16 cols 0..127 ----------
__global__ __launch_bounds__(256) void conv_fix(
    const float* __restrict__ convAcc, const float* __restrict__ conv_b,
    u16* __restrict__ qeb) {
  int idx = blockIdx.x * 256 + threadIdx.x;   // 128*196*32
  int row196 = idx >> 5;
  int c0 = (idx & 31) << 2;
  int n = row196 / 196, o = row196 - n * 196;
  size_t row = (size_t)(n * 224 + o);
  const float4 v = *(const float4*)(convAcc + (row << 7) + c0);
  const float4 b = *(const float4*)(conv_b + c0);
  ushort4 pk;
  pk.x = f2b(v.x + b.x); pk.y = f2b(v.y + b.y);
  pk.z = f2b(v.z + b.z); pk.w = f2b(v.w + b.w);
  *(ushort4*)(qeb + row * 288 + c0) = pk;
}

// ---------- generic GEMM skeleton: C[28672, 256] = A[28672,KP]bf16 * Bt[256,KP]^T ----------
// Double-buffered counted-vmcnt pipeline; 4 global_load_lds per wave per K-step.
// A staging padded to 128 rows (row group 7 garbage, never read by MFMA).
template <int MODE, int KP, int KC>
__global__ __launch_bounds__(256) void gemm_kernel(
    const u16* __restrict__ A, const u16* __restrict__ Bt,
    const float* __restrict__ bias, const float* __restrict__ vec,
    float* __restrict__ outF, u16* __restrict__ outB) {
  __shared__ __align__(16) u16 lA[2][128 * 32];
  __shared__ __align__(16) u16 lB[2][128 * 32];
  int tid = threadIdx.x, lane = tid & 63, w = tid >> 6;
  int bx = blockIdx.x, by = blockIdx.y;
  int r0 = bx * 112;
  int cBase = by * 128;
  int kb = (((lane & 3) ^ ((lane >> 3) & 3)) << 3);   // XOR-swizzled source chunk
  int rA0 = r0 + w * 16 + (lane >> 2);
  int rA1 = r0 + (w + 4) * 16 + (lane >> 2);          // group 7 (rows 112..127) = pad
  const u16* gA0 = A + (size_t)rA0 * KP + kb;
  const u16* gA1 = A + (size_t)rA1 * KP + kb;
  int cB0 = cBase + w * 16 + (lane >> 2);
  int cB1 = cBase + (w + 4) * 16 + (lane >> 2);
  const u16* gB0 = Bt + (size_t)cB0 * KP + kb;
  const u16* gB1 = Bt + (size_t)cB1 * KP + kb;

  f32x4 acc[7][2];
#pragma unroll
  for (int mt = 0; mt < 7; ++mt)
#pragma unroll
    for (int j = 0; j < 2; ++j) acc[mt][j] = (f32x4){0.f, 0.f, 0.f, 0.f};
  int colW = w * 32;
  int l = lane & 15, q = lane >> 4;
  int co = ((q ^ ((l >> 1) & 3)) << 3);

  auto STAGE = [&](int buf, int cb) {
    g2l16(gA0 + cb * 32, &lA[buf][w * 512]);
    g2l16(gA1 + cb * 32, &lA[buf][(w + 4) * 512]);
    g2l16(gB0 + cb * 32, &lB[buf][w * 512]);
    g2l16(gB1 + cb * 32, &lB[buf][(w + 4) * 512]);
  };

  auto COMPUTE = [&](int cur) {
    bf16x8 af[7];
#pragma unroll
    for (int mt = 0; mt < 7; ++mt)
      af[mt] = *(const bf16x8*)&lA[cur][(mt * 16 + l) * 32 + co];
#pragma unroll
    for (int j = 0; j < 2; ++j) {
      bf16x8 bfr = *(const bf16x8*)&lB[cur][(colW + j * 16 + l) * 32 + co];
#pragma unroll
      for (int mt = 0; mt < 7; ++mt)
        acc[mt][j] = __builtin_amdgcn_mfma_f32_16x16x32_bf16(af[mt], bfr, acc[mt][j], 0, 0, 0);
    }
  };

  STAGE(0, 0);
#pragma unroll
  for (int it = 0; it < KC - 1; ++it) {
    STAGE((it & 1) ^ 1, it + 1);
    asm volatile("s_waitcnt vmcnt(4)" ::: "memory");   // prev step's 4 loads done; 4 in flight
    __builtin_amdgcn_s_barrier();
    __builtin_amdgcn_sched_barrier(0);
    COMPUTE(it & 1);
    __builtin_amdgcn_sched_barrier(0);
    __builtin_amdgcn_s_barrier();
    __builtin_amdgcn_sched_barrier(0);
  }
  asm volatile("s_waitcnt vmcnt(0)" ::: "memory");
  __builtin_amdgcn_s_barrier();
  __builtin_amdgcn_sched_barrier(0);
  COMPUTE((KC - 1) & 1);

  int q4 = lane >> 4, c = lane & 15;
  if (MODE == 0) {
    float attp[7][4];
#pragma unroll
    for (int mt = 0; mt < 7; ++mt)
#pragma unroll
      for (int r = 0; r < 4; ++r) attp[mt][r] = 0.f;
#pragma unroll
    for (int j = 0; j < 2; ++j) {
      int col = cBase + colW + j * 16 + c;
      float b0 = bias[col], w1 = vec[col];
#pragma unroll
      for (int mt = 0; mt < 7; ++mt)
#pragma unroll
        for (int r = 0; r < 4; ++r) {
          float v = fmaxf(acc[mt][j][r] + b0, 0.f);
          attp[mt][r] += v * w1;
        }
    }
#pragma unroll
    for (int mt = 0; mt < 7; ++mt)
#pragma unroll
      for (int r = 0; r < 4; ++r) {
        float p = attp[mt][r];
        p += __shfl_xor(p, 1, 64);
        p += __shfl_xor(p, 2, 64);
        p += __shfl_xor(p, 4, 64);
        p += __shfl_xor(p, 8, 64);
        if (c == 0) atomicAdd(&outF[r0 + mt * 16 + q4 * 4 + r], p);
      }
  } else if (MODE == 1) {
    int n = bx >> 1;
#pragma unroll
    for (int mt = 0; mt < 7; ++mt)
#pragma unroll
      for (int j = 0; j < 2; ++j) {
        int col = cBase + colW + j * 16 + c;
        float b = bias[n * 256 + col];
#pragma unroll
        for (int r = 0; r < 4; ++r) {
          int row = r0 + mt * 16 + q4 * 4 + r;
          outB[(size_t)row * 256 + col] = f2b(fmaxf(acc[mt][j][r] + b, 0.f));
        }
      }
  } else {
    int n = bx >> 1;
    int ob = (bx & 1) * 112;
#pragma unroll
    for (int j = 0; j < 2; ++j) {
      int col = cBase + colW + j * 16 + c;
      float b = bias[col];
      float sum = 0.f;
#pragma unroll
      for (int mt = 0; mt < 7; ++mt)
#pragma unroll
        for (int r = 0; r < 4; ++r) {
          int o = ob + mt * 16 + q4 * 4 + r;
          if (o < 196) sum += fmaxf(acc[mt][j][r] + b, 0.f);
        }
      sum += __shfl_xor(sum, 16, 64);
      sum += __shfl_xor(sum, 32, 64);
      if (q4 == 0) atomicAdd(&outF[n * 256 + col], sum);
    }
  }
}

// ---------- K5: softmax over objects, soft-select, per-n bias2 ----------
__global__ __launch_bounds__(256) void sel_kernel(
    const float* __restrict__ att, const u16* __restrict__ qeb,
    const float* __restrict__ gt_w0, const float* __restrict__ gt_b0,
    float* __restrict__ bias2) {
  int n = blockIdx.x, t = threadIdx.x;
  int w = t >> 6, lane = t & 63;
  __shared__ u16 sq[196][130];
  __shared__ float sm[196];
  __shared__ float sel[130];
  __shared__ float red[8];
  // cooperative stage of qeb[n, 0:196, 0:130]
  const u16* base = qeb + (size_t)n * 224 * 288;
  for (int o = w; o < 196; o += 4) {
    const u16* rowp = base + (size_t)o * 288;
    for (int c = lane; c < 130; c += 64) sq[o][c] = rowp[c];
  }
  float a = (t < 196) ? att[n * 224 + t] : -1e30f;
  float m = a;
  for (int mask = 1; mask < 64; mask <<= 1) m = fmaxf(m, __shfl_xor(m, mask, 64));
  if (lane == 0) red[w] = m;
  __syncthreads();
  float M = fmaxf(fmaxf(red[0], red[1]), fmaxf(red[2], red[3]));
  float e = (t < 196) ? expf(a - M) : 0.f;
  float sAcc = e;
  for (int mask = 1; mask < 64; mask <<= 1) sAcc += __shfl_xor(sAcc, mask, 64);
  if (lane == 0) red[4 + w] = sAcc;
  __syncthreads();
  float S = red[4] + red[5] + red[6] + red[7];
  if (t < 196) sm[t] = e / S;
  __syncthreads();
  if (t < 130) {
    float acc = 0.f;
    for (int o = 0; o < 196; ++o) acc += sm[o] * b2f(sq[o][t]);
    sel[t] = acc;
  }
  __syncthreads();
  float acc2 = gt_b0[t];
  for (int d = 0; d < 130; ++d) acc2 += sel[d] * gt_w0[(258 + d) * 256 + t];
  bias2[n * 256 + t] = acc2;
}

// ---------- K8: f_phi ----------
__global__ __launch_bounds__(256) void fphi(
    const float* __restrict__ relations, const float* __restrict__ fp_w0,
    const float* __restrict__ fp_b0, const float* __restrict__ fp_w1,
    const float* __restrict__ fp_b1, float* __restrict__ out) {
  int n = blockIdx.x, t = threadIdx.x;
  __shared__ float rel[256];
  __shared__ float f[256];
  rel[t] = relations[n * 256 + t];
  __syncthreads();
  float acc = fp_b0[t];
  for (int k = 0; k < 256; ++k) acc += rel[k] * fp_w0[k * 256 + t];
  f[t] = fmaxf(acc, 0.f);
  __syncthreads();
  if (t < 32) {
    float o = fp_b1[0];
    for (int k = 0; k < 256; ++k) o += f[k] * fp_w1[k * 32 + t];
    out[n * 32 + t] = o;
  }
}

extern "C" void kernel_launch(void* const* d_in, const int* in_sizes, int n_in,
                              void* d_out, int out_size, void* d_ws, size_t ws_size,
                              hipStream_t stream) {
  const float* image = (const float*)d_in[0];
  const float* code = (const float*)d_in[1];
  const float* conv_w = (const float*)d_in[2];
  const float* conv_b = (const float*)d_in[3];
  const float* hp_w0 = (const float*)d_in[4];
  const float* hp_b0 = (const float*)d_in[5];
  const float* hp_w1 = (const float*)d_in[6];
  /* hp_b1: softmax shift-invariant, dropped */
  const float* gt_w0 = (const float*)d_in[8];
  const float* gt_b0 = (const float*)d_in[9];
  const float* gt_w1 = (const float*)d_in[10];
  const float* gt_b1 = (const float*)d_in[11];
  const float* fp_w0 = (const float*)d_in[12];
  const float* fp_b0 = (const float*)d_in[13];
  const float* fp_w1 = (const float*)d_in[14];
  const float* fp_b1 = (const float*)d_in[15];
  float* out = (float*)d_out;

  char* p = (char*)d_ws;
  u16* imgT = (u16*)p;   p += (size_t)128 * 256 * 1024 * 2;   // 67.1 MB
  u16* W2 = (u16*)p;     p += (size_t)9 * 128 * 1024 * 2;     // 2.36 MB
  u16* qeb = (u16*)p;    p += (size_t)ROWS * 288 * 2;         // 16.5 MB
  u16* hp_w0t = (u16*)p; p += (size_t)256 * 288 * 2;
  u16* gt_w0t = (u16*)p; p += (size_t)256 * 288 * 2;
  u16* gt_w1t = (u16*)p; p += (size_t)256 * 256 * 2;
  float* att = (float*)p;   p += (size_t)ROWS * 4;
  float* bias2 = (float*)p; p += (size_t)128 * 256 * 4;
  float* convAcc = (float*)p; p += (size_t)ROWS * 128 * 4;    // 14.7 MB; reused as g1
  float* relations = (float*)p; p += (size_t)128 * 256 * 4;
  u16* g1 = (u16*)convAcc;   // alias: convAcc dead after conv_fix, g1 born at MODE1

  hipMemsetAsync(att, 0, (size_t)ROWS * 4, stream);
  hipMemsetAsync(relations, 0, (size_t)128 * 256 * 4, stream);
  hipMemsetAsync(convAcc, 0, (size_t)ROWS * 128 * 4, stream);

  prep_weights<<<5440, 256, 0, stream>>>(conv_w, hp_w0, gt_w0, gt_w1, W2, hp_w0t, gt_w0t, gt_w1t);
  prep_img<<<2048, 256, 0, stream>>>(image, imgT);
  fill_qe<<<ROWS / 8, 256, 0, stream>>>(code, qeb);
  conv_gemm<<<512, 256, 0, stream>>>(imgT, W2, convAcc);
  conv_fix<<<3136, 256, 0, stream>>>(convAcc, conv_b, qeb);
  gemm_kernel<0, 288, 9><<<dim3(256, 2), 256, 0, stream>>>(qeb, hp_w0t, hp_b0, hp_w1, att, nullptr);
  sel_kernel<<<128, 256, 0, stream>>>(att, qeb, gt_w0, gt_b0, bias2);
  gemm_kernel<1, 288, 9><<<dim3(256, 2), 256, 0, stream>>>(qeb, gt_w0t, bias2, nullptr, nullptr, g1);
  gemm_kernel<2, 256, 8><<<dim3(256, 2), 256, 0, stream>>>(g1, gt_w1t, gt_b1, nullptr, relations, nullptr);
  fphi<<<128, 256, 0, stream>>>(relations, fp_w0, fp_b0, fp_w1, fp_b1, out);
}